// Round 6
// baseline (1664.309 us; speedup 1.0000x reference)
//
#include <hip/hip_runtime.h>
#include <hip/hip_bf16.h>

// ---------------------------------------------------------------------------
// SwinTransformerBlockAdapter round 5: double-buffered (2-phase) MFMA GEMM —
// prefetch next K-tile while computing current (latency-bound fix).
// ---------------------------------------------------------------------------

#define TOK 25088
#define TELEM 9633792L  // 25088*384

typedef __attribute__((ext_vector_type(4))) float f32x4;
typedef __attribute__((ext_vector_type(8))) short bf16x8;
typedef __attribute__((address_space(3))) unsigned int as3_u32;
typedef __attribute__((address_space(1))) const unsigned int as1_u32;

__device__ __forceinline__ float ldAny(const void* p, long i, int bf) {
  if (bf) return __bfloat162float(((const __hip_bfloat16*)p)[i]);
  return ((const float*)p)[i];
}
__device__ __forceinline__ void stAny(void* p, long i, int bf, float v) {
  if (bf) ((__hip_bfloat16*)p)[i] = __float2bfloat16(v);
  else ((float*)p)[i] = v;
}

__global__ void detect_dtype(const unsigned int* __restrict__ w, int* flag) {
  __shared__ int cnt;
  if (threadIdx.x == 0) cnt = 0;
  __syncthreads();
  int local = 0;
  for (int i = threadIdx.x; i < 4096; i += blockDim.x) {
    unsigned int lo = w[i] & 0xFFFFu;
    unsigned int e = (lo >> 7) & 0xFFu;
    if ((e >= 100u && e <= 135u) || lo == 0u) local++;
  }
  atomicAdd(&cnt, local);
  __syncthreads();
  if (threadIdx.x == 0) *flag = (cnt > 2600) ? 1 : 0;
}

// ---------------------------------------------------------------------------
// Weight transpose + cast: in [K,N] (raw flagged) -> out bf16 [N,K].
// ---------------------------------------------------------------------------
__global__ __launch_bounds__(256) void transpose_to_bf16(
    const void* __restrict__ in, __hip_bfloat16* __restrict__ out, int K,
    int N, const int* __restrict__ flagp) {
  int bf = *flagp;
  __shared__ float tile[32][33];
  int nb = blockIdx.x * 32, kb = blockIdx.y * 32;
  int tx = threadIdx.x & 31, ty = threadIdx.x >> 5;  // 32 x 8
#pragma unroll
  for (int r = 0; r < 32; r += 8)
    tile[ty + r][tx] = ldAny(in, (long)(kb + ty + r) * N + nb + tx, bf);
  __syncthreads();
#pragma unroll
  for (int r = 0; r < 32; r += 8)
    out[(long)(nb + ty + r) * K + kb + tx] = __float2bfloat16(tile[tx][ty + r]);
}

// ---------------------------------------------------------------------------
// bf16 MFMA GEMM, double-buffered: C[M,N] = A[M,K]@B with BT [N,K] given.
// 128x128 tile, BK=32, 4 waves, each wave 64x64 (4x4 frags of 16x16x32).
// Pipeline: stage(buf0); sync; loop { stage(buf^1, t+1); compute buf; sync }.
// Staging per matrix per K-step: 2 global_load_lds(16B); wave w issue i
// covers rows [i*64+w*16, +16); lane l -> row +(l>>2), col (l&3)*8 (linear).
// Epilogue: +bias (raw flagged), optional exact gelu, optional accum.
// cmode: 0 = C bf16 ws; 1 = C raw d_out (flagged) at element coff.
// M,N multiples of 128; K multiple of 32.
// ---------------------------------------------------------------------------
__global__ __launch_bounds__(256) void gemm_bf16(
    const __hip_bfloat16* __restrict__ A, const __hip_bfloat16* __restrict__ BT,
    const void* __restrict__ bias, void* __restrict__ C, int cmode, long coff,
    int accum, int doGelu, int M, int N, int K, const int* __restrict__ flagp) {
  const int bf = *flagp;
  __shared__ __hip_bfloat16 As[2][128 * 32];
  __shared__ __hip_bfloat16 Bs[2][128 * 32];
  const int tid = threadIdx.x;
  const int lane = tid & 63, wave = tid >> 6;
  const int wr = wave >> 1, wc = wave & 1;
  const long m0 = (long)blockIdx.y * 128;
  const int n0 = blockIdx.x * 128;
  f32x4 acc[4][4] = {};

  const int srow = wave * 16 + (lane >> 2);  // staging row, issue 0
  const int scol = (lane & 3) * 8;
  const __hip_bfloat16* pA0 = A + (m0 + srow) * K + scol;
  const __hip_bfloat16* pB0 = BT + (long)(n0 + srow) * K + scol;
  const long rstep = 64 * (long)K;  // issue-1 row offset
  const int lds0 = (wave * 16) * 32;
  const int lds1 = (64 + wave * 16) * 32;

  const int row = lane & 15;
  const int kk = (lane >> 4) * 8;
  const int nt = K / 32;

  auto stage = [&](int buf, int k0) {
    __builtin_amdgcn_global_load_lds((as1_u32*)(pA0 + k0),
                                     (as3_u32*)(&As[buf][lds0]), 16, 0, 0);
    __builtin_amdgcn_global_load_lds((as1_u32*)(pA0 + rstep + k0),
                                     (as3_u32*)(&As[buf][lds1]), 16, 0, 0);
    __builtin_amdgcn_global_load_lds((as1_u32*)(pB0 + k0),
                                     (as3_u32*)(&Bs[buf][lds0]), 16, 0, 0);
    __builtin_amdgcn_global_load_lds((as1_u32*)(pB0 + rstep + k0),
                                     (as3_u32*)(&Bs[buf][lds1]), 16, 0, 0);
  };

  stage(0, 0);
  __syncthreads();
  int cur = 0;
  for (int t = 0; t < nt; ++t) {
    if (t + 1 < nt) stage(cur ^ 1, (t + 1) * 32);
    bf16x8 af[4], bfr[4];
#pragma unroll
    for (int i = 0; i < 4; ++i)
      af[i] = *(const bf16x8*)(&As[cur][(wr * 64 + i * 16 + row) * 32 + kk]);
#pragma unroll
    for (int j = 0; j < 4; ++j)
      bfr[j] = *(const bf16x8*)(&Bs[cur][(wc * 64 + j * 16 + row) * 32 + kk]);
#pragma unroll
    for (int i = 0; i < 4; ++i)
#pragma unroll
      for (int j = 0; j < 4; ++j)
        acc[i][j] = __builtin_amdgcn_mfma_f32_16x16x32_bf16(af[i], bfr[j],
                                                            acc[i][j], 0, 0, 0);
    __syncthreads();  // drains prefetch vmcnt + protects LDS
    cur ^= 1;
  }

  const int crow = (lane >> 4) * 4;
  const int ccol = lane & 15;
#pragma unroll
  for (int i = 0; i < 4; ++i) {
#pragma unroll
    for (int r = 0; r < 4; ++r) {
      long m = m0 + wr * 64 + i * 16 + crow + r;
#pragma unroll
      for (int j = 0; j < 4; ++j) {
        int n = n0 + wc * 64 + j * 16 + ccol;
        float v = acc[i][j][r];
        if (bias) v += ldAny(bias, n, bf);
        if (doGelu) v = 0.5f * v * (1.f + erff(v * 0.70710678118f));
        long idx = m * (long)N + n;
        if (cmode == 0) {
          ((__hip_bfloat16*)C)[idx] = __float2bfloat16(v);
        } else {
          long odx = coff + idx;
          if (accum) v += ldAny(C, odx, bf);
          stAny(C, odx, bf, v);
        }
      }
    }
  }
}

// ---------------------------------------------------------------------------
// Generic f32 GEMM for the small adapter matmuls (N=16/48/384, K<=384).
// ---------------------------------------------------------------------------
#define BM 64
#define BN 64
#define BK 16

__global__ __launch_bounds__(256) void gemm_f32(
    const void* __restrict__ A, int Araw, const void* __restrict__ B,
    const void* __restrict__ bias, void* __restrict__ C, int Craw, long coff,
    int accum, int doGelu, const void* __restrict__ add1, int a1raw,
    const void* __restrict__ add2, int a2raw, int M, int N, int K,
    const int* __restrict__ flagp) {
  const int bf = *flagp;
  const int abf = Araw ? bf : 0;
  __shared__ float As[BK][BM + 1];
  __shared__ float Bs[BK][BN + 1];
  const int tid = threadIdx.x;
  const int tx = tid & 15, ty = tid >> 4;
  const int n0 = blockIdx.x * BN;
  const long m0 = (long)blockIdx.y * BM;
  float acc[4][4] = {};
  for (int k0 = 0; k0 < K; k0 += BK) {
#pragma unroll
    for (int r = 0; r < 4; ++r) {
      int m = (tid >> 4) + r * 16;
      int k = tid & 15;
      As[k][m] = ldAny(A, (m0 + m) * K + (k0 + k), abf);
    }
#pragma unroll
    for (int r = 0; r < 4; ++r) {
      int n = tid & 63;
      int k = (tid >> 6) + r * 4;
      int gn = n0 + n;
      Bs[k][n] = (gn < N) ? ldAny(B, (long)(k0 + k) * N + gn, bf) : 0.f;
    }
    __syncthreads();
#pragma unroll
    for (int kk = 0; kk < BK; ++kk) {
      float a[4], b[4];
#pragma unroll
      for (int i = 0; i < 4; ++i) a[i] = As[kk][ty + i * 16];
#pragma unroll
      for (int j = 0; j < 4; ++j) b[j] = Bs[kk][tx + j * 16];
#pragma unroll
      for (int i = 0; i < 4; ++i)
#pragma unroll
        for (int j = 0; j < 4; ++j) acc[i][j] += a[i] * b[j];
    }
    __syncthreads();
  }
#pragma unroll
  for (int i = 0; i < 4; ++i) {
    long row = m0 + ty + i * 16;
#pragma unroll
    for (int j = 0; j < 4; ++j) {
      int col = n0 + tx + j * 16;
      if (col >= N) continue;
      float v = acc[i][j];
      if (bias) v += ldAny(bias, col, bf);
      if (doGelu) v = 0.5f * v * (1.f + erff(v * 0.70710678118f));
      long idx = row * (long)N + col;
      if (add1) v += ldAny(add1, idx, a1raw ? bf : 0);
      if (add2) v += ldAny(add2, idx, a2raw ? bf : 0);
      long odx = coff + idx;
      if (Craw) {
        if (accum) v += ldAny(C, odx, bf);
        stAny(C, odx, bf, v);
      } else {
        if (accum) v += ((float*)C)[odx];
        ((float*)C)[odx] = v;
      }
    }
  }
}

// ---------------------------------------------------------------------------
// LayerNorm over C=384, output bf16 (feeds MFMA GEMMs).
// ---------------------------------------------------------------------------
__global__ __launch_bounds__(128) void ln_kernel(
    const void* __restrict__ X, int xraw, const void* __restrict__ g,
    const void* __restrict__ b, __hip_bfloat16* __restrict__ out,
    const int* __restrict__ flagp) {
  int bf = *flagp;
  int xbf = xraw ? bf : 0;
  long t = blockIdx.x;
  int tid = threadIdx.x;
  float v[3];
  float s = 0.f;
#pragma unroll
  for (int r = 0; r < 3; ++r) {
    v[r] = ldAny(X, t * 384 + tid + r * 128, xbf);
    s += v[r];
  }
  __shared__ float red[2], red2[2];
  for (int off = 32; off; off >>= 1) s += __shfl_down(s, off, 64);
  if ((tid & 63) == 0) red[tid >> 6] = s;
  __syncthreads();
  float mean = (red[0] + red[1]) * (1.f / 384.f);
  float var = 0.f;
#pragma unroll
  for (int r = 0; r < 3; ++r) {
    float d = v[r] - mean;
    var += d * d;
  }
  for (int off = 32; off; off >>= 1) var += __shfl_down(var, off, 64);
  if ((tid & 63) == 0) red2[tid >> 6] = var;
  __syncthreads();
  float rstd = rsqrtf((red2[0] + red2[1]) * (1.f / 384.f) + 1e-5f);
#pragma unroll
  for (int r = 0; r < 3; ++r) {
    int c = tid + r * 128;
    out[t * 384 + c] = __float2bfloat16((v[r] - mean) * rstd *
                                        ldAny(g, c, bf) + ldAny(b, c, bf));
  }
}

// ---------------------------------------------------------------------------
// Windowed attention, one block per (window, head). qkv bf16 [25088,1152]
// in image-token order; z-branch pre-shift folded into the gather.
// ---------------------------------------------------------------------------
__global__ __launch_bounds__(256) void attn_kernel(
    const __hip_bfloat16* __restrict__ qkv, const void* __restrict__ rpb,
    __hip_bfloat16* __restrict__ outp, int shifted,
    const int* __restrict__ maskz, const int* __restrict__ flagp) {
  int bf = *flagp;
  int blk = blockIdx.x;
  int head = blk % 12;
  int win = blk / 12;
  int b = win >> 6;
  int wh = (win >> 3) & 7;
  int ww = win & 7;
  __shared__ float q[49][33], k[49][33], vv[49][33];
  __shared__ float sc[49][50];
  int tid = threadIdx.x;
  bool useMask = shifted && (*maskz != 0);
  for (int idx = tid; idx < 49 * 32; idx += 256) {
    int n = idx >> 5, dc = idx & 31;
    int i = n / 7, j = n % 7;
    int h = wh * 7 + i, w = ww * 7 + j;
    if (shifted) {
      h = (h + 3) % 56;
      w = (w + 3) % 56;
    }
    long t = ((long)b * 56 + h) * 56 + w;
    long base = t * 1152 + head * 32 + dc;
    q[n][dc] = __bfloat162float(qkv[base]);
    k[n][dc] = __bfloat162float(qkv[base + 384]);
    vv[n][dc] = __bfloat162float(qkv[base + 768]);
  }
  __syncthreads();
  const float scale = 0.17677669529663687f;  // 1/sqrt(32)
  for (int s = tid; s < 49 * 49; s += 256) {
    int n = s / 49, m = s % 49;
    float d = 0.f;
#pragma unroll
    for (int c = 0; c < 32; ++c) d += q[n][c] * k[m][c];
    d *= scale;
    int in_ = n / 7, jn = n % 7, im = m / 7, jm = m % 7;
    int ridx = (in_ - im + 6) * 13 + (jn - jm + 6);
    d += ldAny(rpb, (long)ridx * 12 + head, bf);
    if (useMask) {
      int hn = wh * 7 + in_, wn = ww * 7 + jn;
      int hm = wh * 7 + im, wm = ww * 7 + jm;
      int rn = (hn < 49 ? 0 : (hn < 53 ? 1 : 2)) * 3 +
               (wn < 49 ? 0 : (wn < 53 ? 1 : 2));
      int rm = (hm < 49 ? 0 : (hm < 53 ? 1 : 2)) * 3 +
               (wm < 49 ? 0 : (wm < 53 ? 1 : 2));
      if (rn != rm) d -= 100.f;
    }
    sc[n][m] = d;
  }
  __syncthreads();
  if (tid < 49) {
    float mx = -1e30f;
    for (int m = 0; m < 49; ++m) mx = fmaxf(mx, sc[tid][m]);
    float sum = 0.f;
    for (int m = 0; m < 49; ++m) {
      float e = expf(sc[tid][m] - mx);
      sc[tid][m] = e;
      sum += e;
    }
    float inv = 1.f / sum;
    for (int m = 0; m < 49; ++m) sc[tid][m] *= inv;
  }
  __syncthreads();
  for (int o = tid; o < 49 * 32; o += 256) {
    int n = o >> 5, dc = o & 31;
    float acc = 0.f;
    for (int m = 0; m < 49; ++m) acc += sc[n][m] * vv[m][dc];
    outp[((long)win * 49 + n) * 384 + head * 32 + dc] = __float2bfloat16(acc);
  }
}

// ---------------------------------------------------------------------------
// Window-reverse + roll(+3,+3) from d_out (raw flagged) into f32 ws.
// ---------------------------------------------------------------------------
__global__ __launch_bounds__(384) void unroll_kernel(
    const void* __restrict__ aw, long aoff, float* __restrict__ out,
    const int* __restrict__ flagp) {
  int bf = *flagp;
  long t = blockIdx.x;
  int c = threadIdx.x;
  int b = (int)(t / 3136);
  int hw = (int)(t % 3136);
  int h = hw / 56, w = hw % 56;
  int hp = (h - 3 + 56) % 56, wp = (w - 3 + 56) % 56;
  int win = b * 64 + (hp / 7) * 8 + (wp / 7);
  int n = (hp % 7) * 7 + (wp % 7);
  out[t * 384 + c] = ldAny(aw, aoff + ((long)win * 49 + n) * 384 + c, bf);
}

// ---------------------------------------------------------------------------
extern "C" void kernel_launch(void* const* d_in, const int* in_sizes, int n_in,
                              void* d_out, int out_size, void* d_ws,
                              size_t ws_size, hipStream_t stream) {
  const void* x_FMAG = d_in[0];
  const void* x_in = d_in[1];
  const void* z_in = d_in[2];
  const int* mask_z = (const int*)d_in[3];
  const void* ln1_g = d_in[4];
  const void* ln1_b = d_in[5];
  const void* ln2_g = d_in[6];
  const void* ln2_b = d_in[7];
  const void* w_qkv = d_in[8];
  const void* b_qkv = d_in[9];
  const void* w_proj = d_in[10];
  const void* b_proj = d_in[11];
  const void* rpb = d_in[12];
  const void* w_fc1 = d_in[13];
  const void* b_fc1 = d_in[14];
  const void* w_fc2 = d_in[15];
  const void* b_fc2 = d_in[16];
  const void* st_dw = d_in[17];
  const void* st_db = d_in[18];
  const void* st_uw = d_in[19];
  const void* st_ub = d_in[20];
  const void* t_dw = d_in[21];
  const void* t_db = d_in[22];
  const void* t_uw = d_in[23];
  const void* t_ub = d_in[24];
  const void* t2_dw = d_in[25];
  const void* t2_db = d_in[26];
  const void* t2_uw = d_in[27];
  const void* t2_ub = d_in[28];

  const long T = TELEM;
  char* base = (char*)d_ws;
  float* W0 = (float*)base; base += T * 4;             // shortcut_x
  float* W4 = (float*)base; base += T * 4;             // x_att (unrolled)
  float* W5 = (float*)base; base += T * 4;             // z_att (unrolled)
  float* W6 = (float*)base; base += T * 4;             // x1
  float* W7 = (float*)base; base += T * 4;             // z1
  __hip_bfloat16* Sbf = (__hip_bfloat16*)base; base += T * 2;   // LN/attn out
  __hip_bfloat16* QKVbf = (__hip_bfloat16*)base; base += 3 * T * 2;
  __hip_bfloat16* Hbf = (__hip_bfloat16*)base; base += 4 * T * 2;  // mlp hidden
  float* Hs = (float*)base; base += (long)TOK * 48 * 4;  // adapter hidden
  __hip_bfloat16* TQ = (__hip_bfloat16*)base; base += 384L * 1152 * 2;
  __hip_bfloat16* TP = (__hip_bfloat16*)base; base += 384L * 384 * 2;
  __hip_bfloat16* T1 = (__hip_bfloat16*)base; base += 384L * 1536 * 2;
  __hip_bfloat16* T2 = (__hip_bfloat16*)base; base += 1536L * 384 * 2;
  int* flag = (int*)base;

  detect_dtype<<<1, 256, 0, stream>>>((const unsigned int*)x_FMAG, flag);

  // Weight transposes (bf16 [N,K])
  transpose_to_bf16<<<dim3(1152 / 32, 384 / 32), 256, 0, stream>>>(
      w_qkv, TQ, 384, 1152, flag);
  transpose_to_bf16<<<dim3(384 / 32, 384 / 32), 256, 0, stream>>>(
      w_proj, TP, 384, 384, flag);
  transpose_to_bf16<<<dim3(1536 / 32, 384 / 32), 256, 0, stream>>>(
      w_fc1, T1, 384, 1536, flag);
  transpose_to_bf16<<<dim3(384 / 32, 1536 / 32), 256, 0, stream>>>(
      w_fc2, T2, 1536, 384, flag);

  auto gemmf = [&](const void* A, int Araw, const void* B, const void* bias,
                   void* C, int Craw, long coff, int accum, int gelu,
                   const void* a1, int a1raw, const void* a2, int a2raw, int M,
                   int N, int K) {
    dim3 g((N + BN - 1) / BN, (M + BM - 1) / BM);
    gemm_f32<<<g, 256, 0, stream>>>(A, Araw, B, bias, C, Craw, coff, accum,
                                    gelu, a1, a1raw, a2, a2raw, M, N, K, flag);
  };
  auto gemmb = [&](const __hip_bfloat16* A, const __hip_bfloat16* BT,
                   const void* bias, void* C, int cmode, long coff, int accum,
                   int gelu, int N, int K) {
    dim3 g(N / 128, TOK / 128);
    gemm_bf16<<<g, 256, 0, stream>>>(A, BT, bias, C, cmode, coff, accum, gelu,
                                     TOK, N, K, flag);
  };

  // 1-2: x = gelu(x_FMAG @ st_dw + st_db) @ st_uw + st_ub + x
  gemmf(x_FMAG, 1, st_dw, st_db, Hs, 0, 0, 0, 1, nullptr, 0, nullptr, 0, TOK,
        48, 384);
  gemmf(Hs, 0, st_uw, st_ub, W0, 0, 0, 0, 0, x_in, 1, nullptr, 0, TOK, 384,
        48);
  // x branch attention
  ln_kernel<<<TOK, 128, 0, stream>>>(W0, 0, ln1_g, ln1_b, Sbf, flag);
  gemmb(Sbf, TQ, b_qkv, QKVbf, 0, 0, 0, 0, 1152, 384);
  attn_kernel<<<512 * 12, 256, 0, stream>>>(QKVbf, rpb, Sbf, 0, mask_z, flag);
  gemmb(Sbf, TP, b_proj, d_out, 1, T, 0, 0, 384, 384);  // -> awx4
  unroll_kernel<<<TOK, 384, 0, stream>>>(d_out, T, W4, flag);
  // z branch attention (shifted + masked)
  ln_kernel<<<TOK, 128, 0, stream>>>(z_in, 1, ln1_g, ln1_b, Sbf, flag);
  gemmb(Sbf, TQ, b_qkv, QKVbf, 0, 0, 0, 0, 1152, 384);
  attn_kernel<<<512 * 12, 256, 0, stream>>>(QKVbf, rpb, Sbf, 1, mask_z, flag);
  gemmb(Sbf, TP, b_proj, d_out, 1, 3 * T, 0, 0, 384, 384);  // -> awz4
  unroll_kernel<<<TOK, 384, 0, stream>>>(d_out, 3 * T, W5, flag);
  // x1 = shortcut_x + x_att + ad_t(shortcut_z)
  gemmf(z_in, 1, t_dw, t_db, Hs, 0, 0, 0, 0, nullptr, 0, nullptr, 0, TOK, 16,
        384);
  gemmf(Hs, 0, t_uw, t_ub, W6, 0, 0, 0, 0, W0, 0, W4, 0, TOK, 384, 16);
  // z1 = shortcut_z + z_att + ad_t(shortcut_x)
  gemmf(W0, 0, t_dw, t_db, Hs, 0, 0, 0, 0, nullptr, 0, nullptr, 0, TOK, 16,
        384);
  gemmf(Hs, 0, t_uw, t_ub, W7, 0, 0, 0, 0, z_in, 1, W5, 0, TOK, 384, 16);
  // x2 = x1 + mlp(LN2(x1)) + ad_t2(z1)
  ln_kernel<<<TOK, 128, 0, stream>>>(W6, 0, ln2_g, ln2_b, Sbf, flag);
  gemmb(Sbf, T1, b_fc1, Hbf, 0, 0, 0, 1, 1536, 384);
  gemmf(W7, 0, t2_dw, t2_db, Hs, 0, 0, 0, 0, nullptr, 0, nullptr, 0, TOK, 16,
        384);
  gemmf(Hs, 0, t2_uw, t2_ub, d_out, 1, 0, 0, 0, W6, 0, nullptr, 0, TOK, 384,
        16);  // x2 = ad_t2(z1) + x1
  gemmb(Hbf, T2, b_fc2, d_out, 1, 0, 1, 0, 384, 1536);  // x2 += mlp
  // z2 = z1 + mlp(LN2(z1)) + ad_t2(x1)
  ln_kernel<<<TOK, 128, 0, stream>>>(W7, 0, ln2_g, ln2_b, Sbf, flag);
  gemmb(Sbf, T1, b_fc1, Hbf, 0, 0, 0, 1, 1536, 384);
  gemmf(W6, 0, t2_dw, t2_db, Hs, 0, 0, 0, 0, nullptr, 0, nullptr, 0, TOK, 16,
        384);
  gemmf(Hs, 0, t2_uw, t2_ub, d_out, 1, 2 * T, 0, 0, W7, 0, nullptr, 0, TOK,
        384, 16);
  gemmb(Hbf, T2, b_fc2, d_out, 1, 2 * T, 1, 0, 384, 1536);
}

// Round 7
// 1637.955 us; speedup vs baseline: 1.0161x; 1.0161x over previous
//
#include <hip/hip_runtime.h>
#include <hip/hip_bf16.h>

// ---------------------------------------------------------------------------
// SwinTransformerBlockAdapter round 6:
//  (a) counted-vmcnt 3-deep pipelined MFMA GEMM (raw barriers, never vmcnt(0)
//      mid-loop)  [T4]
//  (b) x/z branches batched through shared-weight GEMMs (M=50176) + batched
//      attention (1024 windows)
// ---------------------------------------------------------------------------

#define TOK 25088
#define TELEM 9633792L  // 25088*384

typedef __attribute__((ext_vector_type(4))) float f32x4;
typedef __attribute__((ext_vector_type(8))) short bf16x8;
typedef __attribute__((address_space(3))) unsigned int as3_u32;
typedef __attribute__((address_space(1))) const unsigned int as1_u32;

// raw-code: 0 = f32 ws, 1 = harness buffer (flagged), 2 = always bf16 ws
__device__ __forceinline__ float ldc(const void* p, long i, int code, int bf) {
  if (code == 1 ? bf : (code == 2))
    return __bfloat162float(((const __hip_bfloat16*)p)[i]);
  return ((const float*)p)[i];
}
__device__ __forceinline__ void stAny(void* p, long i, int bf, float v) {
  if (bf) ((__hip_bfloat16*)p)[i] = __float2bfloat16(v);
  else ((float*)p)[i] = v;
}

__global__ void detect_dtype(const unsigned int* __restrict__ w, int* flag) {
  __shared__ int cnt;
  if (threadIdx.x == 0) cnt = 0;
  __syncthreads();
  int local = 0;
  for (int i = threadIdx.x; i < 4096; i += blockDim.x) {
    unsigned int lo = w[i] & 0xFFFFu;
    unsigned int e = (lo >> 7) & 0xFFu;
    if ((e >= 100u && e <= 135u) || lo == 0u) local++;
  }
  atomicAdd(&cnt, local);
  __syncthreads();
  if (threadIdx.x == 0) *flag = (cnt > 2600) ? 1 : 0;
}

// ---------------------------------------------------------------------------
// Weight transpose + cast: in [K,N] (raw flagged) -> out bf16 [N,K].
// ---------------------------------------------------------------------------
__global__ __launch_bounds__(256) void transpose_to_bf16(
    const void* __restrict__ in, __hip_bfloat16* __restrict__ out, int K,
    int N, const int* __restrict__ flagp) {
  int bf = *flagp;
  __shared__ float tile[32][33];
  int nb = blockIdx.x * 32, kb = blockIdx.y * 32;
  int tx = threadIdx.x & 31, ty = threadIdx.x >> 5;  // 32 x 8
#pragma unroll
  for (int r = 0; r < 32; r += 8)
    tile[ty + r][tx] = ldc(in, (long)(kb + ty + r) * N + nb + tx, 1, bf);
  __syncthreads();
#pragma unroll
  for (int r = 0; r < 32; r += 8)
    out[(long)(nb + ty + r) * K + kb + tx] = __float2bfloat16(tile[tx][ty + r]);
}

// ---------------------------------------------------------------------------
// bf16 MFMA GEMM, 3-deep counted-vmcnt pipeline. C[M,N] = A[M,K]@BT[N,K]^T.
// 128x128 tile, BK=32, 4 waves. Per iter: read frags -> lgkm(0)+barrier ->
// stage(t+2 into same buf) -> MFMA -> vmcnt(4) (counted!) -> barrier.
// Dual output: rows >= Msplit go to coff2 (for batched x/z epilogues).
// cmode: 0 = C bf16 ws; 1 = C raw d_out (flagged). M,N mult of 128, K of 32.
// ---------------------------------------------------------------------------
__global__ __launch_bounds__(256) void gemm_bf16(
    const __hip_bfloat16* __restrict__ A, const __hip_bfloat16* __restrict__ BT,
    const void* __restrict__ bias, void* __restrict__ C, int cmode, long coff,
    long coff2, long Msplit, int accum, int doGelu, int M, int N, int K,
    const int* __restrict__ flagp) {
  const int bf = *flagp;
  __shared__ __hip_bfloat16 As[2][128 * 32];
  __shared__ __hip_bfloat16 Bs[2][128 * 32];
  const int tid = threadIdx.x;
  const int lane = tid & 63, wave = tid >> 6;
  const int wr = wave >> 1, wc = wave & 1;
  const long m0 = (long)blockIdx.y * 128;
  const int n0 = blockIdx.x * 128;
  f32x4 acc[4][4] = {};

  const int srow = wave * 16 + (lane >> 2);
  const int scol = (lane & 3) * 8;
  const __hip_bfloat16* pA0 = A + (m0 + srow) * K + scol;
  const __hip_bfloat16* pB0 = BT + (long)(n0 + srow) * K + scol;
  const long rstep = 64 * (long)K;
  const int lds0 = (wave * 16) * 32;
  const int lds1 = (64 + wave * 16) * 32;

  const int row = lane & 15;
  const int kk = (lane >> 4) * 8;
  const int nt = K / 32;

  auto stage = [&](int buf, int t) {
    const int k0 = t * 32;
    __builtin_amdgcn_global_load_lds((as1_u32*)(pA0 + k0),
                                     (as3_u32*)(&As[buf][lds0]), 16, 0, 0);
    __builtin_amdgcn_global_load_lds((as1_u32*)(pA0 + rstep + k0),
                                     (as3_u32*)(&As[buf][lds1]), 16, 0, 0);
    __builtin_amdgcn_global_load_lds((as1_u32*)(pB0 + k0),
                                     (as3_u32*)(&Bs[buf][lds0]), 16, 0, 0);
    __builtin_amdgcn_global_load_lds((as1_u32*)(pB0 + rstep + k0),
                                     (as3_u32*)(&Bs[buf][lds1]), 16, 0, 0);
  };

  // prologue: stage t=0 and t=1; wait only t=0's loads (4 newest in flight)
  stage(0, 0);
  if (nt > 1) {
    stage(1, 1);
    asm volatile("s_waitcnt vmcnt(4)" ::: "memory");
  } else {
    asm volatile("s_waitcnt vmcnt(0)" ::: "memory");
  }
  __builtin_amdgcn_sched_barrier(0);
  __builtin_amdgcn_s_barrier();

  for (int t = 0; t < nt; ++t) {
    const int cur = t & 1;
    bf16x8 af[4], bfr[4];
#pragma unroll
    for (int i = 0; i < 4; ++i)
      af[i] = *(const bf16x8*)(&As[cur][(wr * 64 + i * 16 + row) * 32 + kk]);
#pragma unroll
    for (int j = 0; j < 4; ++j)
      bfr[j] = *(const bf16x8*)(&Bs[cur][(wc * 64 + j * 16 + row) * 32 + kk]);
    // my reads are in-registers after this; barrier => ALL waves' reads done
    asm volatile("s_waitcnt lgkmcnt(0)" ::: "memory");
    __builtin_amdgcn_sched_barrier(0);
    __builtin_amdgcn_s_barrier();
    if (t + 2 < nt) stage(cur, t + 2);  // overwrite cur buf for tile t+2
#pragma unroll
    for (int i = 0; i < 4; ++i)
#pragma unroll
      for (int j = 0; j < 4; ++j)
        acc[i][j] = __builtin_amdgcn_mfma_f32_16x16x32_bf16(af[i], bfr[j],
                                                            acc[i][j], 0, 0, 0);
    if (t + 1 < nt) {
      if (t + 2 < nt)
        asm volatile("s_waitcnt vmcnt(4)" ::: "memory");  // t+1 landed
      else
        asm volatile("s_waitcnt vmcnt(0)" ::: "memory");  // tail drain
      __builtin_amdgcn_sched_barrier(0);
      __builtin_amdgcn_s_barrier();
    }
  }

  const int crow = (lane >> 4) * 4;
  const int ccol = lane & 15;
#pragma unroll
  for (int i = 0; i < 4; ++i) {
#pragma unroll
    for (int r = 0; r < 4; ++r) {
      long m = m0 + wr * 64 + i * 16 + crow + r;
#pragma unroll
      for (int j = 0; j < 4; ++j) {
        int n = n0 + wc * 64 + j * 16 + ccol;
        float v = acc[i][j][r];
        if (bias) v += ldc(bias, n, 1, bf);
        if (doGelu) v = 0.5f * v * (1.f + erff(v * 0.70710678118f));
        long idx = m * (long)N + n;
        if (cmode == 0) {
          ((__hip_bfloat16*)C)[idx] = __float2bfloat16(v);
        } else {
          long odx = (m < Msplit) ? coff + idx
                                  : coff2 + (m - Msplit) * (long)N + n;
          if (accum) v += ldc(C, odx, 1, bf);
          stAny(C, odx, bf, v);
        }
      }
    }
  }
}

// ---------------------------------------------------------------------------
// Generic f32 GEMM for the small adapter matmuls (N=16/48/384, K<=384).
// A/add1/add2 take raw-codes {0,1,2}; C: 0 = f32 ws, 1 = raw d_out.
// ---------------------------------------------------------------------------
#define BM 64
#define BN 64
#define BK 16

__global__ __launch_bounds__(256) void gemm_f32(
    const void* __restrict__ A, int Ac, const void* __restrict__ B,
    const void* __restrict__ bias, void* __restrict__ C, int Craw, long coff,
    int accum, int doGelu, const void* __restrict__ add1, int a1c,
    const void* __restrict__ add2, int a2c, int M, int N, int K,
    const int* __restrict__ flagp) {
  const int bf = *flagp;
  __shared__ float As[BK][BM + 1];
  __shared__ float Bs[BK][BN + 1];
  const int tid = threadIdx.x;
  const int tx = tid & 15, ty = tid >> 4;
  const int n0 = blockIdx.x * BN;
  const long m0 = (long)blockIdx.y * BM;
  float acc[4][4] = {};
  for (int k0 = 0; k0 < K; k0 += BK) {
#pragma unroll
    for (int r = 0; r < 4; ++r) {
      int m = (tid >> 4) + r * 16;
      int k = tid & 15;
      As[k][m] = ldc(A, (m0 + m) * K + (k0 + k), Ac, bf);
    }
#pragma unroll
    for (int r = 0; r < 4; ++r) {
      int n = tid & 63;
      int k = (tid >> 6) + r * 4;
      int gn = n0 + n;
      Bs[k][n] = (gn < N) ? ldc(B, (long)(k0 + k) * N + gn, 1, bf) : 0.f;
    }
    __syncthreads();
#pragma unroll
    for (int kk = 0; kk < BK; ++kk) {
      float a[4], b[4];
#pragma unroll
      for (int i = 0; i < 4; ++i) a[i] = As[kk][ty + i * 16];
#pragma unroll
      for (int j = 0; j < 4; ++j) b[j] = Bs[kk][tx + j * 16];
#pragma unroll
      for (int i = 0; i < 4; ++i)
#pragma unroll
        for (int j = 0; j < 4; ++j) acc[i][j] += a[i] * b[j];
    }
    __syncthreads();
  }
#pragma unroll
  for (int i = 0; i < 4; ++i) {
    long row = m0 + ty + i * 16;
#pragma unroll
    for (int j = 0; j < 4; ++j) {
      int col = n0 + tx + j * 16;
      if (col >= N) continue;
      float v = acc[i][j];
      if (bias) v += ldc(bias, col, 1, bf);
      if (doGelu) v = 0.5f * v * (1.f + erff(v * 0.70710678118f));
      long idx = row * (long)N + col;
      if (add1) v += ldc(add1, idx, a1c, bf);
      if (add2) v += ldc(add2, idx, a2c, bf);
      long odx = coff + idx;
      if (Craw) {
        if (accum) v += ldc(C, odx, 1, bf);
        stAny(C, odx, bf, v);
      } else {
        if (accum) v += ((float*)C)[odx];
        ((float*)C)[odx] = v;
      }
    }
  }
}

// ---------------------------------------------------------------------------
// LayerNorm over C=384, output bf16.
// ---------------------------------------------------------------------------
__global__ __launch_bounds__(128) void ln_kernel(
    const void* __restrict__ X, int xc, const void* __restrict__ g,
    const void* __restrict__ b, __hip_bfloat16* __restrict__ out,
    const int* __restrict__ flagp) {
  int bf = *flagp;
  long t = blockIdx.x;
  int tid = threadIdx.x;
  float v[3];
  float s = 0.f;
#pragma unroll
  for (int r = 0; r < 3; ++r) {
    v[r] = ldc(X, t * 384 + tid + r * 128, xc, bf);
    s += v[r];
  }
  __shared__ float red[2], red2[2];
  for (int off = 32; off; off >>= 1) s += __shfl_down(s, off, 64);
  if ((tid & 63) == 0) red[tid >> 6] = s;
  __syncthreads();
  float mean = (red[0] + red[1]) * (1.f / 384.f);
  float var = 0.f;
#pragma unroll
  for (int r = 0; r < 3; ++r) {
    float d = v[r] - mean;
    var += d * d;
  }
  for (int off = 32; off; off >>= 1) var += __shfl_down(var, off, 64);
  if ((tid & 63) == 0) red2[tid >> 6] = var;
  __syncthreads();
  float rstd = rsqrtf((red2[0] + red2[1]) * (1.f / 384.f) + 1e-5f);
#pragma unroll
  for (int r = 0; r < 3; ++r) {
    int c = tid + r * 128;
    out[t * 384 + c] = __float2bfloat16((v[r] - mean) * rstd *
                                        ldc(g, c, 1, bf) + ldc(b, c, 1, bf));
  }
}

// ---------------------------------------------------------------------------
// Batched windowed attention: 1024 windows x 12 heads. win<512 => x branch
// (unshifted, qkv rows 0..TOK); win>=512 => z branch (shifted +3 gather,
// masked, qkv rows TOK..2TOK). Output rows win*49+n (0..50175).
// ---------------------------------------------------------------------------
__global__ __launch_bounds__(256) void attn_kernel(
    const __hip_bfloat16* __restrict__ qkv, const void* __restrict__ rpb,
    __hip_bfloat16* __restrict__ outp, const int* __restrict__ maskz,
    const int* __restrict__ flagp) {
  int bf = *flagp;
  int blk = blockIdx.x;
  int head = blk % 12;
  int win = blk / 12;
  int shifted = (win >= 512) ? 1 : 0;
  int wn = win & 511;
  int b = wn >> 6;
  int wh = (wn >> 3) & 7;
  int ww = wn & 7;
  __shared__ float q[49][33], k[49][33], vv[49][33];
  __shared__ float sc[49][50];
  int tid = threadIdx.x;
  bool useMask = shifted && (*maskz != 0);
  const long tokoff = shifted ? (long)TOK : 0;
  for (int idx = tid; idx < 49 * 32; idx += 256) {
    int n = idx >> 5, dc = idx & 31;
    int i = n / 7, j = n % 7;
    int h = wh * 7 + i, w = ww * 7 + j;
    if (shifted) {
      h = (h + 3) % 56;
      w = (w + 3) % 56;
    }
    long t = tokoff + ((long)b * 56 + h) * 56 + w;
    long base = t * 1152 + head * 32 + dc;
    q[n][dc] = __bfloat162float(qkv[base]);
    k[n][dc] = __bfloat162float(qkv[base + 384]);
    vv[n][dc] = __bfloat162float(qkv[base + 768]);
  }
  __syncthreads();
  const float scale = 0.17677669529663687f;  // 1/sqrt(32)
  for (int s = tid; s < 49 * 49; s += 256) {
    int n = s / 49, m = s % 49;
    float d = 0.f;
#pragma unroll
    for (int c = 0; c < 32; ++c) d += q[n][c] * k[m][c];
    d *= scale;
    int in_ = n / 7, jn = n % 7, im = m / 7, jm = m % 7;
    int ridx = (in_ - im + 6) * 13 + (jn - jm + 6);
    d += ldc(rpb, (long)ridx * 12 + head, 1, bf);
    if (useMask) {
      int hn = wh * 7 + in_, wn2 = ww * 7 + jn;
      int hm = wh * 7 + im, wm = ww * 7 + jm;
      int rn = (hn < 49 ? 0 : (hn < 53 ? 1 : 2)) * 3 +
               (wn2 < 49 ? 0 : (wn2 < 53 ? 1 : 2));
      int rm = (hm < 49 ? 0 : (hm < 53 ? 1 : 2)) * 3 +
               (wm < 49 ? 0 : (wm < 53 ? 1 : 2));
      if (rn != rm) d -= 100.f;
    }
    sc[n][m] = d;
  }
  __syncthreads();
  if (tid < 49) {
    float mx = -1e30f;
    for (int m = 0; m < 49; ++m) mx = fmaxf(mx, sc[tid][m]);
    float sum = 0.f;
    for (int m = 0; m < 49; ++m) {
      float e = expf(sc[tid][m] - mx);
      sc[tid][m] = e;
      sum += e;
    }
    float inv = 1.f / sum;
    for (int m = 0; m < 49; ++m) sc[tid][m] *= inv;
  }
  __syncthreads();
  for (int o = tid; o < 49 * 32; o += 256) {
    int n = o >> 5, dc = o & 31;
    float acc = 0.f;
    for (int m = 0; m < 49; ++m) acc += sc[n][m] * vv[m][dc];
    outp[((long)win * 49 + n) * 384 + head * 32 + dc] = __float2bfloat16(acc);
  }
}

// ---------------------------------------------------------------------------
// Batched window-reverse + roll(+3,+3): blocks 0..2*TOK-1. First half reads
// awx (d_out@aoff1) -> o1 bf16; second half reads awz (d_out@aoff2) -> o2.
// ---------------------------------------------------------------------------
__global__ __launch_bounds__(384) void unroll_kernel(
    const void* __restrict__ dout, long aoff1, long aoff2,
    __hip_bfloat16* __restrict__ o1, __hip_bfloat16* __restrict__ o2,
    const int* __restrict__ flagp) {
  int bf = *flagp;
  long t = blockIdx.x;
  int c = threadIdx.x;
  int half = t >= TOK;
  long tt = half ? t - TOK : t;
  int b = (int)(tt / 3136);
  int hw = (int)(tt % 3136);
  int h = hw / 56, w = hw % 56;
  int hp = (h - 3 + 56) % 56, wp = (w - 3 + 56) % 56;
  int win = b * 64 + (hp / 7) * 8 + (wp / 7);
  int n = (hp % 7) * 7 + (wp % 7);
  long aoff = half ? aoff2 : aoff1;
  float v = ldc(dout, aoff + ((long)win * 49 + n) * 384 + c, 1, bf);
  (half ? o2 : o1)[tt * 384 + c] = __float2bfloat16(v);
}

// ---------------------------------------------------------------------------
extern "C" void kernel_launch(void* const* d_in, const int* in_sizes, int n_in,
                              void* d_out, int out_size, void* d_ws,
                              size_t ws_size, hipStream_t stream) {
  const void* x_FMAG = d_in[0];
  const void* x_in = d_in[1];
  const void* z_in = d_in[2];
  const int* mask_z = (const int*)d_in[3];
  const void* ln1_g = d_in[4];
  const void* ln1_b = d_in[5];
  const void* ln2_g = d_in[6];
  const void* ln2_b = d_in[7];
  const void* w_qkv = d_in[8];
  const void* b_qkv = d_in[9];
  const void* w_proj = d_in[10];
  const void* b_proj = d_in[11];
  const void* rpb = d_in[12];
  const void* w_fc1 = d_in[13];
  const void* b_fc1 = d_in[14];
  const void* w_fc2 = d_in[15];
  const void* b_fc2 = d_in[16];
  const void* st_dw = d_in[17];
  const void* st_db = d_in[18];
  const void* st_uw = d_in[19];
  const void* st_ub = d_in[20];
  const void* t_dw = d_in[21];
  const void* t_db = d_in[22];
  const void* t_uw = d_in[23];
  const void* t_ub = d_in[24];
  const void* t2_dw = d_in[25];
  const void* t2_db = d_in[26];
  const void* t2_uw = d_in[27];
  const void* t2_ub = d_in[28];

  const long T = TELEM;
  char* base = (char*)d_ws;
  float* W6 = (float*)base; base += T * 4;  // x1
  float* W7 = (float*)base; base += T * 4;  // z1
  __hip_bfloat16* Sbf = (__hip_bfloat16*)base; base += 2 * T * 2;  // 2T bf16
  char* D = base; base += 16 * T;  // overlay region (16T bytes)
  float* W0 = (float*)D;                               // shortcut_x (f32 T)
  __hip_bfloat16* QKVbf = (__hip_bfloat16*)(D + T * 4);  // 6T bf16
  __hip_bfloat16* W4bf = QKVbf;                          // x_att (after attn)
  __hip_bfloat16* W5bf = QKVbf + T;                      // z_att
  __hip_bfloat16* Hbf = (__hip_bfloat16*)D;              // mlp hidden 8T bf16
  float* Hs = (float*)base; base += (long)TOK * 48 * 4;  // adapter hidden
  __hip_bfloat16* TQ = (__hip_bfloat16*)base; base += 384L * 1152 * 2;
  __hip_bfloat16* TP = (__hip_bfloat16*)base; base += 384L * 384 * 2;
  __hip_bfloat16* T1 = (__hip_bfloat16*)base; base += 384L * 1536 * 2;
  __hip_bfloat16* T2 = (__hip_bfloat16*)base; base += 1536L * 384 * 2;
  int* flag = (int*)base;

  detect_dtype<<<1, 256, 0, stream>>>((const unsigned int*)x_FMAG, flag);

  transpose_to_bf16<<<dim3(1152 / 32, 384 / 32), 256, 0, stream>>>(
      w_qkv, TQ, 384, 1152, flag);
  transpose_to_bf16<<<dim3(384 / 32, 384 / 32), 256, 0, stream>>>(
      w_proj, TP, 384, 384, flag);
  transpose_to_bf16<<<dim3(1536 / 32, 384 / 32), 256, 0, stream>>>(
      w_fc1, T1, 384, 1536, flag);
  transpose_to_bf16<<<dim3(384 / 32, 1536 / 32), 256, 0, stream>>>(
      w_fc2, T2, 1536, 384, flag);

  auto gemmf = [&](const void* A, int Ac, const void* B, const void* bias,
                   void* C, int Craw, long coff, int accum, int gelu,
                   const void* a1, int a1c, const void* a2, int a2c, int M,
                   int N, int K) {
    dim3 g((N + BN - 1) / BN, (M + BM - 1) / BM);
    gemm_f32<<<g, 256, 0, stream>>>(A, Ac, B, bias, C, Craw, coff, accum,
                                    gelu, a1, a1c, a2, a2c, M, N, K, flag);
  };
  auto gemmb = [&](const __hip_bfloat16* A, const __hip_bfloat16* BT,
                   const void* bias, void* C, int cmode, long coff, long coff2,
                   long msplit, int accum, int gelu, int M, int N, int K) {
    dim3 g(N / 128, M / 128);
    gemm_bf16<<<g, 256, 0, stream>>>(A, BT, bias, C, cmode, coff, coff2,
                                     msplit, accum, gelu, M, N, K, flag);
  };

  // st adapter: W0 = gelu(x_FMAG@st_dw+st_db)@st_uw + st_ub + x
  gemmf(x_FMAG, 1, st_dw, st_db, Hs, 0, 0, 0, 1, nullptr, 0, nullptr, 0, TOK,
        48, 384);
  gemmf(Hs, 0, st_uw, st_ub, W0, 0, 0, 0, 0, x_in, 1, nullptr, 0, TOK, 384,
        48);
  // LN1 both branches -> Sbf halves
  ln_kernel<<<TOK, 128, 0, stream>>>(W0, 0, ln1_g, ln1_b, Sbf, flag);
  ln_kernel<<<TOK, 128, 0, stream>>>(z_in, 1, ln1_g, ln1_b, Sbf + T, flag);
  // batched qkv (M=2*TOK)
  gemmb(Sbf, TQ, b_qkv, QKVbf, 0, 0, 0, 2 * TOK, 0, 0, 2 * TOK, 1152, 384);
  // batched attention (1024 windows x 12 heads) -> Sbf
  attn_kernel<<<1024 * 12, 256, 0, stream>>>(QKVbf, rpb, Sbf, mask_z, flag);
  // batched proj -> awx4 (d_out@T) / awz4 (d_out@3T)
  gemmb(Sbf, TP, b_proj, d_out, 1, T, 3 * T, TOK, 0, 0, 2 * TOK, 384, 384);
  // batched unroll -> W4bf, W5bf
  unroll_kernel<<<2 * TOK, 384, 0, stream>>>(d_out, T, 3 * T, W4bf, W5bf,
                                             flag);
  // x1 = W0 + W4 + ad_t(z_in)
  gemmf(z_in, 1, t_dw, t_db, Hs, 0, 0, 0, 0, nullptr, 0, nullptr, 0, TOK, 16,
        384);
  gemmf(Hs, 0, t_uw, t_ub, W6, 0, 0, 0, 0, W0, 0, W4bf, 2, TOK, 384, 16);
  // z1 = z_in + W5 + ad_t(W0)
  gemmf(W0, 0, t_dw, t_db, Hs, 0, 0, 0, 0, nullptr, 0, nullptr, 0, TOK, 16,
        384);
  gemmf(Hs, 0, t_uw, t_ub, W7, 0, 0, 0, 0, z_in, 1, W5bf, 2, TOK, 384, 16);
  // LN2 both -> Sbf halves
  ln_kernel<<<TOK, 128, 0, stream>>>(W6, 0, ln2_g, ln2_b, Sbf, flag);
  ln_kernel<<<TOK, 128, 0, stream>>>(W7, 0, ln2_g, ln2_b, Sbf + T, flag);
  // batched fc1 (gelu) -> Hbf
  gemmb(Sbf, T1, b_fc1, Hbf, 0, 0, 0, 2 * TOK, 0, 1, 2 * TOK, 1536, 384);
  // x2 partial = ad_t2(z1) + x1 -> d_out@0 ; z2 partial -> d_out@2T
  gemmf(W7, 0, t2_dw, t2_db, Hs, 0, 0, 0, 0, nullptr, 0, nullptr, 0, TOK, 16,
        384);
  gemmf(Hs, 0, t2_uw, t2_ub, d_out, 1, 0, 0, 0, W6, 0, nullptr, 0, TOK, 384,
        16);
  gemmf(W6, 0, t2_dw, t2_db, Hs, 0, 0, 0, 0, nullptr, 0, nullptr, 0, TOK, 16,
        384);
  gemmf(Hs, 0, t2_uw, t2_ub, d_out, 1, 2 * T, 0, 0, W7, 0, nullptr, 0, TOK,
        384, 16);
  // batched fc2 accum -> x2 (@0) / z2 (@2T)
  gemmb(Hbf, T2, b_fc2, d_out, 1, 0, 2 * T, TOK, 1, 0, 2 * TOK, 384, 1536);
}

// Round 8
// 1503.139 us; speedup vs baseline: 1.1072x; 1.0897x over previous
//
#include <hip/hip_runtime.h>
#include <hip/hip_bf16.h>

// ---------------------------------------------------------------------------
// SwinTransformerBlockAdapter round 7: MFMA attention (one wave per
// (window,head)), bias+mask precomputed table. GEMMs unchanged from round 6.
// ---------------------------------------------------------------------------

#define TOK 25088
#define TELEM 9633792L  // 25088*384

typedef __attribute__((ext_vector_type(4))) float f32x4;
typedef __attribute__((ext_vector_type(8))) short bf16x8;
typedef __attribute__((address_space(3))) unsigned int as3_u32;
typedef __attribute__((address_space(1))) const unsigned int as1_u32;

// raw-code: 0 = f32 ws, 1 = harness buffer (flagged), 2 = always bf16 ws
__device__ __forceinline__ float ldc(const void* p, long i, int code, int bf) {
  if (code == 1 ? bf : (code == 2))
    return __bfloat162float(((const __hip_bfloat16*)p)[i]);
  return ((const float*)p)[i];
}
__device__ __forceinline__ void stAny(void* p, long i, int bf, float v) {
  if (bf) ((__hip_bfloat16*)p)[i] = __float2bfloat16(v);
  else ((float*)p)[i] = v;
}

__global__ void detect_dtype(const unsigned int* __restrict__ w, int* flag) {
  __shared__ int cnt;
  if (threadIdx.x == 0) cnt = 0;
  __syncthreads();
  int local = 0;
  for (int i = threadIdx.x; i < 4096; i += blockDim.x) {
    unsigned int lo = w[i] & 0xFFFFu;
    unsigned int e = (lo >> 7) & 0xFFu;
    if ((e >= 100u && e <= 135u) || lo == 0u) local++;
  }
  atomicAdd(&cnt, local);
  __syncthreads();
  if (threadIdx.x == 0) *flag = (cnt > 2600) ? 1 : 0;
}

// ---------------------------------------------------------------------------
// Weight transpose + cast: in [K,N] (raw flagged) -> out bf16 [N,K].
// ---------------------------------------------------------------------------
__global__ __launch_bounds__(256) void transpose_to_bf16(
    const void* __restrict__ in, __hip_bfloat16* __restrict__ out, int K,
    int N, const int* __restrict__ flagp) {
  int bf = *flagp;
  __shared__ float tile[32][33];
  int nb = blockIdx.x * 32, kb = blockIdx.y * 32;
  int tx = threadIdx.x & 31, ty = threadIdx.x >> 5;  // 32 x 8
#pragma unroll
  for (int r = 0; r < 32; r += 8)
    tile[ty + r][tx] = ldc(in, (long)(kb + ty + r) * N + nb + tx, 1, bf);
  __syncthreads();
#pragma unroll
  for (int r = 0; r < 32; r += 8)
    out[(long)(nb + ty + r) * K + kb + tx] = __float2bfloat16(tile[tx][ty + r]);
}

// ---------------------------------------------------------------------------
// Bias+mask table: tab[cls][head][n][m], cls = maskEdge class
// (bit1: wh==7 shifted-edge, bit0: ww==7). 48*2401 entries.
// ---------------------------------------------------------------------------
__global__ __launch_bounds__(256) void build_tab(const void* __restrict__ rpb,
                                                 float* __restrict__ tab,
                                                 const int* __restrict__ flagp) {
  int bf = *flagp;
  int idx = blockIdx.x * 256 + threadIdx.x;
  if (idx >= 48 * 2401) return;
  int m = idx % 49;
  int n = (idx / 49) % 49;
  int head = (idx / 2401) % 12;
  int cls = idx / (2401 * 12);
  int in_ = n / 7, jn = n % 7, im = m / 7, jm = m % 7;
  int ridx = (in_ - im + 6) * 13 + (jn - jm + 6);
  float v = ldc(rpb, (long)ridx * 12 + head, 1, bf);
  int whE = (cls >> 1) & 1, wwE = cls & 1;
  int rhn = whE ? (in_ < 4 ? 1 : 2) : 0;
  int rwn = wwE ? (jn < 4 ? 1 : 2) : 0;
  int rhm = whE ? (im < 4 ? 1 : 2) : 0;
  int rwm = wwE ? (jm < 4 ? 1 : 2) : 0;
  if ((rhn * 3 + rwn) != (rhm * 3 + rwm)) v -= 100.f;
  tab[idx] = v;
}

// ---------------------------------------------------------------------------
// bf16 MFMA GEMM, 3-deep counted-vmcnt pipeline (unchanged, round 6).
// ---------------------------------------------------------------------------
__global__ __launch_bounds__(256) void gemm_bf16(
    const __hip_bfloat16* __restrict__ A, const __hip_bfloat16* __restrict__ BT,
    const void* __restrict__ bias, void* __restrict__ C, int cmode, long coff,
    long coff2, long Msplit, int accum, int doGelu, int M, int N, int K,
    const int* __restrict__ flagp) {
  const int bf = *flagp;
  __shared__ __hip_bfloat16 As[2][128 * 32];
  __shared__ __hip_bfloat16 Bs[2][128 * 32];
  const int tid = threadIdx.x;
  const int lane = tid & 63, wave = tid >> 6;
  const int wr = wave >> 1, wc = wave & 1;
  const long m0 = (long)blockIdx.y * 128;
  const int n0 = blockIdx.x * 128;
  f32x4 acc[4][4] = {};

  const int srow = wave * 16 + (lane >> 2);
  const int scol = (lane & 3) * 8;
  const __hip_bfloat16* pA0 = A + (m0 + srow) * K + scol;
  const __hip_bfloat16* pB0 = BT + (long)(n0 + srow) * K + scol;
  const long rstep = 64 * (long)K;
  const int lds0 = (wave * 16) * 32;
  const int lds1 = (64 + wave * 16) * 32;

  const int row = lane & 15;
  const int kk = (lane >> 4) * 8;
  const int nt = K / 32;

  auto stage = [&](int buf, int t) {
    const int k0 = t * 32;
    __builtin_amdgcn_global_load_lds((as1_u32*)(pA0 + k0),
                                     (as3_u32*)(&As[buf][lds0]), 16, 0, 0);
    __builtin_amdgcn_global_load_lds((as1_u32*)(pA0 + rstep + k0),
                                     (as3_u32*)(&As[buf][lds1]), 16, 0, 0);
    __builtin_amdgcn_global_load_lds((as1_u32*)(pB0 + k0),
                                     (as3_u32*)(&Bs[buf][lds0]), 16, 0, 0);
    __builtin_amdgcn_global_load_lds((as1_u32*)(pB0 + rstep + k0),
                                     (as3_u32*)(&Bs[buf][lds1]), 16, 0, 0);
  };

  stage(0, 0);
  if (nt > 1) {
    stage(1, 1);
    asm volatile("s_waitcnt vmcnt(4)" ::: "memory");
  } else {
    asm volatile("s_waitcnt vmcnt(0)" ::: "memory");
  }
  __builtin_amdgcn_sched_barrier(0);
  __builtin_amdgcn_s_barrier();

  for (int t = 0; t < nt; ++t) {
    const int cur = t & 1;
    bf16x8 af[4], bfr[4];
#pragma unroll
    for (int i = 0; i < 4; ++i)
      af[i] = *(const bf16x8*)(&As[cur][(wr * 64 + i * 16 + row) * 32 + kk]);
#pragma unroll
    for (int j = 0; j < 4; ++j)
      bfr[j] = *(const bf16x8*)(&Bs[cur][(wc * 64 + j * 16 + row) * 32 + kk]);
    asm volatile("s_waitcnt lgkmcnt(0)" ::: "memory");
    __builtin_amdgcn_sched_barrier(0);
    __builtin_amdgcn_s_barrier();
    if (t + 2 < nt) stage(cur, t + 2);
#pragma unroll
    for (int i = 0; i < 4; ++i)
#pragma unroll
      for (int j = 0; j < 4; ++j)
        acc[i][j] = __builtin_amdgcn_mfma_f32_16x16x32_bf16(af[i], bfr[j],
                                                            acc[i][j], 0, 0, 0);
    if (t + 1 < nt) {
      if (t + 2 < nt)
        asm volatile("s_waitcnt vmcnt(4)" ::: "memory");
      else
        asm volatile("s_waitcnt vmcnt(0)" ::: "memory");
      __builtin_amdgcn_sched_barrier(0);
      __builtin_amdgcn_s_barrier();
    }
  }

  const int crow = (lane >> 4) * 4;
  const int ccol = lane & 15;
#pragma unroll
  for (int i = 0; i < 4; ++i) {
#pragma unroll
    for (int r = 0; r < 4; ++r) {
      long m = m0 + wr * 64 + i * 16 + crow + r;
#pragma unroll
      for (int j = 0; j < 4; ++j) {
        int n = n0 + wc * 64 + j * 16 + ccol;
        float v = acc[i][j][r];
        if (bias) v += ldc(bias, n, 1, bf);
        if (doGelu) v = 0.5f * v * (1.f + erff(v * 0.70710678118f));
        long idx = m * (long)N + n;
        if (cmode == 0) {
          ((__hip_bfloat16*)C)[idx] = __float2bfloat16(v);
        } else {
          long odx = (m < Msplit) ? coff + idx
                                  : coff2 + (m - Msplit) * (long)N + n;
          if (accum) v += ldc(C, odx, 1, bf);
          stAny(C, odx, bf, v);
        }
      }
    }
  }
}

// ---------------------------------------------------------------------------
// Generic f32 GEMM for the small adapter matmuls (unchanged).
// ---------------------------------------------------------------------------
#define BM 64
#define BN 64
#define BK 16

__global__ __launch_bounds__(256) void gemm_f32(
    const void* __restrict__ A, int Ac, const void* __restrict__ B,
    const void* __restrict__ bias, void* __restrict__ C, int Craw, long coff,
    int accum, int doGelu, const void* __restrict__ add1, int a1c,
    const void* __restrict__ add2, int a2c, int M, int N, int K,
    const int* __restrict__ flagp) {
  const int bf = *flagp;
  __shared__ float As[BK][BM + 1];
  __shared__ float Bs[BK][BN + 1];
  const int tid = threadIdx.x;
  const int tx = tid & 15, ty = tid >> 4;
  const int n0 = blockIdx.x * BN;
  const long m0 = (long)blockIdx.y * BM;
  float acc[4][4] = {};
  for (int k0 = 0; k0 < K; k0 += BK) {
#pragma unroll
    for (int r = 0; r < 4; ++r) {
      int m = (tid >> 4) + r * 16;
      int k = tid & 15;
      As[k][m] = ldc(A, (m0 + m) * K + (k0 + k), Ac, bf);
    }
#pragma unroll
    for (int r = 0; r < 4; ++r) {
      int n = tid & 63;
      int k = (tid >> 6) + r * 4;
      int gn = n0 + n;
      Bs[k][n] = (gn < N) ? ldc(B, (long)(k0 + k) * N + gn, 1, bf) : 0.f;
    }
    __syncthreads();
#pragma unroll
    for (int kk = 0; kk < BK; ++kk) {
      float a[4], b[4];
#pragma unroll
      for (int i = 0; i < 4; ++i) a[i] = As[kk][ty + i * 16];
#pragma unroll
      for (int j = 0; j < 4; ++j) b[j] = Bs[kk][tx + j * 16];
#pragma unroll
      for (int i = 0; i < 4; ++i)
#pragma unroll
        for (int j = 0; j < 4; ++j) acc[i][j] += a[i] * b[j];
    }
    __syncthreads();
  }
#pragma unroll
  for (int i = 0; i < 4; ++i) {
    long row = m0 + ty + i * 16;
#pragma unroll
    for (int j = 0; j < 4; ++j) {
      int col = n0 + tx + j * 16;
      if (col >= N) continue;
      float v = acc[i][j];
      if (bias) v += ldc(bias, col, 1, bf);
      if (doGelu) v = 0.5f * v * (1.f + erff(v * 0.70710678118f));
      long idx = row * (long)N + col;
      if (add1) v += ldc(add1, idx, a1c, bf);
      if (add2) v += ldc(add2, idx, a2c, bf);
      long odx = coff + idx;
      if (Craw) {
        if (accum) v += ldc(C, odx, 1, bf);
        stAny(C, odx, bf, v);
      } else {
        if (accum) v += ((float*)C)[odx];
        ((float*)C)[odx] = v;
      }
    }
  }
}

// ---------------------------------------------------------------------------
// LayerNorm over C=384, output bf16 (unchanged).
// ---------------------------------------------------------------------------
__global__ __launch_bounds__(128) void ln_kernel(
    const void* __restrict__ X, int xc, const void* __restrict__ g,
    const void* __restrict__ b, __hip_bfloat16* __restrict__ out,
    const int* __restrict__ flagp) {
  int bf = *flagp;
  long t = blockIdx.x;
  int tid = threadIdx.x;
  float v[3];
  float s = 0.f;
#pragma unroll
  for (int r = 0; r < 3; ++r) {
    v[r] = ldc(X, t * 384 + tid + r * 128, xc, bf);
    s += v[r];
  }
  __shared__ float red[2], red2[2];
  for (int off = 32; off; off >>= 1) s += __shfl_down(s, off, 64);
  if ((tid & 63) == 0) red[tid >> 6] = s;
  __syncthreads();
  float mean = (red[0] + red[1]) * (1.f / 384.f);
  float var = 0.f;
#pragma unroll
  for (int r = 0; r < 3; ++r) {
    float d = v[r] - mean;
    var += d * d;
  }
  for (int off = 32; off; off >>= 1) var += __shfl_down(var, off, 64);
  if ((tid & 63) == 0) red2[tid >> 6] = var;
  __syncthreads();
  float rstd = rsqrtf((red2[0] + red2[1]) * (1.f / 384.f) + 1e-5f);
#pragma unroll
  for (int r = 0; r < 3; ++r) {
    int c = tid + r * 128;
    out[t * 384 + c] = __float2bfloat16((v[r] - mean) * rstd *
                                        ldc(g, c, 1, bf) + ldc(b, c, 1, bf));
  }
}

// ---------------------------------------------------------------------------
// MFMA windowed attention. One wave per (win,head); 4 waves/block.
// win<512 = x branch (unshifted, qkv rows 0..TOK); win>=512 = z branch
// (shifted gather, masked via table cls). 49 padded to 64; pad K-cols zeroed
// at P; pad Q-rows clamped (finite, never stored).
// Per-wave LDS: P[64][72] bf16 + VT[32][72] bf16 (stride 144B, 16B-aligned).
// ---------------------------------------------------------------------------
__global__ __launch_bounds__(256) void attn_mfma(
    const __hip_bfloat16* __restrict__ qkv, const float* __restrict__ tab,
    __hip_bfloat16* __restrict__ outp, const int* __restrict__ maskz) {
  __shared__ __hip_bfloat16 lds[4][64 * 72 + 32 * 72];
  const int wave = threadIdx.x >> 6, lane = threadIdx.x & 63;
  const int pair = blockIdx.x * 4 + wave;
  const int head = pair % 12;
  const int win = pair / 12;
  const int shifted = win >= 512;
  const int wn = win & 511;
  const int b = wn >> 6, wh = (wn >> 3) & 7, ww = wn & 7;
  const int useMask = shifted && (*maskz != 0);
  const int cls = useMask ? (((wh == 7) ? 2 : 0) | ((ww == 7) ? 1 : 0)) : 0;
  const float* tb = tab + (long)(cls * 12 + head) * 2401;
  __hip_bfloat16* P = lds[wave];
  __hip_bfloat16* VT = lds[wave] + 64 * 72;

  auto tokOf = [&](int n) -> long {
    n = (n < 49) ? n : 0;
    int i = n / 7, j = n % 7;
    int h = wh * 7 + i, w = ww * 7 + j;
    if (shifted) {
      h = (h + 3) % 56;
      w = (w + 3) % 56;
    }
    return (shifted ? (long)TOK : 0) + ((long)b * 56 + h) * 56 + w;
  };

  const int fr = lane & 15;   // row-in-tile / C col
  const int fq = lane >> 4;   // k-group / C row-group
  // --- load Q,K fragments direct from global ---
  bf16x8 qf[4], kf[4];
#pragma unroll
  for (int i = 0; i < 4; ++i) {
    long t = tokOf(i * 16 + fr);
    const __hip_bfloat16* basep = qkv + t * 1152 + head * 32 + fq * 8;
    qf[i] = *(const bf16x8*)(basep);
    kf[i] = *(const bf16x8*)(basep + 384);
  }
  // --- stage V^T into LDS (zero pad cols 48.. first, n=48 overwritten) ---
  for (int e = lane; e < 32 * 16; e += 64)
    VT[(e >> 4) * 72 + 48 + (e & 15)] = __float2bfloat16(0.f);
  for (int e = lane; e < 49 * 32; e += 64) {
    int n = e >> 5, d = e & 31;
    VT[d * 72 + n] = qkv[tokOf(n) * 1152 + 768 + head * 32 + d];
  }
  // --- S = Q K^T (16 MFMA) ---
  f32x4 acc[4][4] = {};
#pragma unroll
  for (int i = 0; i < 4; ++i)
#pragma unroll
    for (int j = 0; j < 4; ++j)
      acc[i][j] =
          __builtin_amdgcn_mfma_f32_16x16x32_bf16(qf[i], kf[j], acc[i][j], 0, 0, 0);
  // --- scale + bias/mask + softmax (rows n = i*16+fq*4+r, cols m = j*16+fr)
  const float scale = 0.17677669529663687f;
#pragma unroll
  for (int i = 0; i < 4; ++i) {
#pragma unroll
    for (int r = 0; r < 4; ++r) {
      int n = i * 16 + fq * 4 + r;
      float s[4];
      float mx = -1e30f;
#pragma unroll
      for (int j = 0; j < 4; ++j) {
        int m = j * 16 + fr;
        float v = acc[i][j][r] * scale;
        if (m < 49 && n < 49) v += tb[n * 49 + m];
        s[j] = (m < 49) ? v : -1e30f;
        mx = fmaxf(mx, s[j]);
      }
#pragma unroll
      for (int d = 1; d < 16; d <<= 1) mx = fmaxf(mx, __shfl_xor(mx, d));
      float sum = 0.f;
#pragma unroll
      for (int j = 0; j < 4; ++j) {
        float p = (16 * j + fr < 49) ? __expf(s[j] - mx) : 0.f;
        s[j] = p;
        sum += p;
      }
#pragma unroll
      for (int d = 1; d < 16; d <<= 1) sum += __shfl_xor(sum, d);
      float inv = 1.f / sum;
#pragma unroll
      for (int j = 0; j < 4; ++j)
        P[n * 72 + j * 16 + fr] = __float2bfloat16(s[j] * inv);
    }
  }
  // --- out = P V (16 MFMA); A-frags from P, B-frags from VT ---
  f32x4 o[4][2] = {};
#pragma unroll
  for (int ks = 0; ks < 2; ++ks) {
    bf16x8 pa[4], vb[2];
#pragma unroll
    for (int i2 = 0; i2 < 4; ++i2)
      pa[i2] = *(const bf16x8*)(P + (i2 * 16 + fr) * 72 + ks * 32 + fq * 8);
#pragma unroll
    for (int j2 = 0; j2 < 2; ++j2)
      vb[j2] = *(const bf16x8*)(VT + (j2 * 16 + fr) * 72 + ks * 32 + fq * 8);
#pragma unroll
    for (int i2 = 0; i2 < 4; ++i2)
#pragma unroll
      for (int j2 = 0; j2 < 2; ++j2)
        o[i2][j2] =
            __builtin_amdgcn_mfma_f32_16x16x32_bf16(pa[i2], vb[j2], o[i2][j2], 0, 0, 0);
  }
  // --- store (rows n<49): out[(win*49+n)*384 + head*32 + d] ---
#pragma unroll
  for (int i2 = 0; i2 < 4; ++i2) {
#pragma unroll
    for (int r = 0; r < 4; ++r) {
      int n = i2 * 16 + fq * 4 + r;
      if (n < 49) {
#pragma unroll
        for (int j2 = 0; j2 < 2; ++j2)
          outp[((long)win * 49 + n) * 384 + head * 32 + j2 * 16 + fr] =
              __float2bfloat16(o[i2][j2][r]);
      }
    }
  }
}

// ---------------------------------------------------------------------------
// Batched window-reverse + roll(+3,+3) (unchanged).
// ---------------------------------------------------------------------------
__global__ __launch_bounds__(384) void unroll_kernel(
    const void* __restrict__ dout, long aoff1, long aoff2,
    __hip_bfloat16* __restrict__ o1, __hip_bfloat16* __restrict__ o2,
    const int* __restrict__ flagp) {
  int bf = *flagp;
  long t = blockIdx.x;
  int c = threadIdx.x;
  int half = t >= TOK;
  long tt = half ? t - TOK : t;
  int b = (int)(tt / 3136);
  int hw = (int)(tt % 3136);
  int h = hw / 56, w = hw % 56;
  int hp = (h - 3 + 56) % 56, wp = (w - 3 + 56) % 56;
  int win = b * 64 + (hp / 7) * 8 + (wp / 7);
  int n = (hp % 7) * 7 + (wp % 7);
  long aoff = half ? aoff2 : aoff1;
  float v = ldc(dout, aoff + ((long)win * 49 + n) * 384 + c, 1, bf);
  (half ? o2 : o1)[tt * 384 + c] = __float2bfloat16(v);
}

// ---------------------------------------------------------------------------
extern "C" void kernel_launch(void* const* d_in, const int* in_sizes, int n_in,
                              void* d_out, int out_size, void* d_ws,
                              size_t ws_size, hipStream_t stream) {
  const void* x_FMAG = d_in[0];
  const void* x_in = d_in[1];
  const void* z_in = d_in[2];
  const int* mask_z = (const int*)d_in[3];
  const void* ln1_g = d_in[4];
  const void* ln1_b = d_in[5];
  const void* ln2_g = d_in[6];
  const void* ln2_b = d_in[7];
  const void* w_qkv = d_in[8];
  const void* b_qkv = d_in[9];
  const void* w_proj = d_in[10];
  const void* b_proj = d_in[11];
  const void* rpb = d_in[12];
  const void* w_fc1 = d_in[13];
  const void* b_fc1 = d_in[14];
  const void* w_fc2 = d_in[15];
  const void* b_fc2 = d_in[16];
  const void* st_dw = d_in[17];
  const void* st_db = d_in[18];
  const void* st_uw = d_in[19];
  const void* st_ub = d_in[20];
  const void* t_dw = d_in[21];
  const void* t_db = d_in[22];
  const void* t_uw = d_in[23];
  const void* t_ub = d_in[24];
  const void* t2_dw = d_in[25];
  const void* t2_db = d_in[26];
  const void* t2_uw = d_in[27];
  const void* t2_ub = d_in[28];

  const long T = TELEM;
  char* base = (char*)d_ws;
  float* W6 = (float*)base; base += T * 4;  // x1
  float* W7 = (float*)base; base += T * 4;  // z1
  __hip_bfloat16* Sbf = (__hip_bfloat16*)base; base += 2 * T * 2;  // 2T bf16
  char* D = base; base += 16 * T;  // overlay region (16T bytes)
  float* W0 = (float*)D;                                 // shortcut_x (f32 T)
  __hip_bfloat16* QKVbf = (__hip_bfloat16*)(D + T * 4);  // 6T bf16
  __hip_bfloat16* W4bf = QKVbf;                          // x_att (after attn)
  __hip_bfloat16* W5bf = QKVbf + T;                      // z_att
  __hip_bfloat16* Hbf = (__hip_bfloat16*)D;              // mlp hidden 8T bf16
  float* Hs = (float*)base; base += (long)TOK * 48 * 4;  // adapter hidden
  __hip_bfloat16* TQ = (__hip_bfloat16*)base; base += 384L * 1152 * 2;
  __hip_bfloat16* TP = (__hip_bfloat16*)base; base += 384L * 384 * 2;
  __hip_bfloat16* T1 = (__hip_bfloat16*)base; base += 384L * 1536 * 2;
  __hip_bfloat16* T2 = (__hip_bfloat16*)base; base += 1536L * 384 * 2;
  float* tab = (float*)base; base += 48L * 2401 * 4;
  int* flag = (int*)base;

  detect_dtype<<<1, 256, 0, stream>>>((const unsigned int*)x_FMAG, flag);

  transpose_to_bf16<<<dim3(1152 / 32, 384 / 32), 256, 0, stream>>>(
      w_qkv, TQ, 384, 1152, flag);
  transpose_to_bf16<<<dim3(384 / 32, 384 / 32), 256, 0, stream>>>(
      w_proj, TP, 384, 384, flag);
  transpose_to_bf16<<<dim3(1536 / 32, 384 / 32), 256, 0, stream>>>(
      w_fc1, T1, 384, 1536, flag);
  transpose_to_bf16<<<dim3(384 / 32, 1536 / 32), 256, 0, stream>>>(
      w_fc2, T2, 1536, 384, flag);
  build_tab<<<(48 * 2401 + 255) / 256, 256, 0, stream>>>(rpb, tab, flag);

  auto gemmf = [&](const void* A, int Ac, const void* B, const void* bias,
                   void* C, int Craw, long coff, int accum, int gelu,
                   const void* a1, int a1c, const void* a2, int a2c, int M,
                   int N, int K) {
    dim3 g((N + BN - 1) / BN, (M + BM - 1) / BM);
    gemm_f32<<<g, 256, 0, stream>>>(A, Ac, B, bias, C, Craw, coff, accum,
                                    gelu, a1, a1c, a2, a2c, M, N, K, flag);
  };
  auto gemmb = [&](const __hip_bfloat16* A, const __hip_bfloat16* BT,
                   const void* bias, void* C, int cmode, long coff, long coff2,
                   long msplit, int accum, int gelu, int M, int N, int K) {
    dim3 g(N / 128, M / 128);
    gemm_bf16<<<g, 256, 0, stream>>>(A, BT, bias, C, cmode, coff, coff2,
                                     msplit, accum, gelu, M, N, K, flag);
  };

  // st adapter: W0 = gelu(x_FMAG@st_dw+st_db)@st_uw + st_ub + x
  gemmf(x_FMAG, 1, st_dw, st_db, Hs, 0, 0, 0, 1, nullptr, 0, nullptr, 0, TOK,
        48, 384);
  gemmf(Hs, 0, st_uw, st_ub, W0, 0, 0, 0, 0, x_in, 1, nullptr, 0, TOK, 384,
        48);
  // LN1 both branches -> Sbf halves
  ln_kernel<<<TOK, 128, 0, stream>>>(W0, 0, ln1_g, ln1_b, Sbf, flag);
  ln_kernel<<<TOK, 128, 0, stream>>>(z_in, 1, ln1_g, ln1_b, Sbf + T, flag);
  // batched qkv (M=2*TOK)
  gemmb(Sbf, TQ, b_qkv, QKVbf, 0, 0, 0, 2 * TOK, 0, 0, 2 * TOK, 1152, 384);
  // batched MFMA attention (1024 win x 12 heads, 4 waves/block) -> Sbf
  attn_mfma<<<1024 * 12 / 4, 256, 0, stream>>>(QKVbf, tab, Sbf, mask_z);
  // batched proj -> awx4 (d_out@T) / awz4 (d_out@3T)
  gemmb(Sbf, TP, b_proj, d_out, 1, T, 3 * T, TOK, 0, 0, 2 * TOK, 384, 384);
  // batched unroll -> W4bf, W5bf
  unroll_kernel<<<2 * TOK, 384, 0, stream>>>(d_out, T, 3 * T, W4bf, W5bf,
                                             flag);
  // x1 = W0 + W4 + ad_t(z_in)
  gemmf(z_in, 1, t_dw, t_db, Hs, 0, 0, 0, 0, nullptr, 0, nullptr, 0, TOK, 16,
        384);
  gemmf(Hs, 0, t_uw, t_ub, W6, 0, 0, 0, 0, W0, 0, W4bf, 2, TOK, 384, 16);
  // z1 = z_in + W5 + ad_t(W0)
  gemmf(W0, 0, t_dw, t_db, Hs, 0, 0, 0, 0, nullptr, 0, nullptr, 0, TOK, 16,
        384);
  gemmf(Hs, 0, t_uw, t_ub, W7, 0, 0, 0, 0, z_in, 1, W5bf, 2, TOK, 384, 16);
  // LN2 both -> Sbf halves
  ln_kernel<<<TOK, 128, 0, stream>>>(W6, 0, ln2_g, ln2_b, Sbf, flag);
  ln_kernel<<<TOK, 128, 0, stream>>>(W7, 0, ln2_g, ln2_b, Sbf + T, flag);
  // batched fc1 (gelu) -> Hbf
  gemmb(Sbf, T1, b_fc1, Hbf, 0, 0, 0, 2 * TOK, 0, 1, 2 * TOK, 1536, 384);
  // x2 partial = ad_t2(z1) + x1 -> d_out@0 ; z2 partial -> d_out@2T
  gemmf(W7, 0, t2_dw, t2_db, Hs, 0, 0, 0, 0, nullptr, 0, nullptr, 0, TOK, 16,
        384);
  gemmf(Hs, 0, t2_uw, t2_ub, d_out, 1, 0, 0, 0, W6, 0, nullptr, 0, TOK, 384,
        16);
  gemmf(W6, 0, t2_dw, t2_db, Hs, 0, 0, 0, 0, nullptr, 0, nullptr, 0, TOK, 16,
        384);
  gemmf(Hs, 0, t2_uw, t2_ub, d_out, 1, 2 * T, 0, 0, W7, 0, nullptr, 0, TOK,
        384, 16);
  // batched fc2 accum -> x2 (@0) / z2 (@2T)
  gemmb(Hbf, T2, b_fc2, d_out, 1, 0, 2 * T, TOK, 1, 0, 2 * TOK, 384, 1536);
}